// Round 3
// baseline (1187.837 us; speedup 1.0000x reference)
//
#include <hip/hip_runtime.h>

// MoE block: router(top-2 of 8) -> per-expert [M,1024]@[1024,4096] GELU
// -> [M,4096]@[4096,1024] -> scale/combine -> residual + LayerNorm.
// bf16 MFMA (16x16x32), fp32 router/accum/epilogue.
// R3: split-K=2 gemm2 with scaled fp32 atomicAdd combine into acc buffer;
//     LN reads x+acc (no gather); cvt folded into router; paired u32 H stores.

#define T_TOKENS 8192
#define DM 1024
#define DF 4096
#define NE 8

typedef unsigned short u16;
typedef short v8s __attribute__((ext_vector_type(8)));
typedef float v4f __attribute__((ext_vector_type(4)));

__device__ __forceinline__ u16 f2bf(float f) {
  unsigned u = __float_as_uint(f);
  u += 0x7FFFu + ((u >> 16) & 1u);
  return (u16)(u >> 16);
}

// async global -> LDS, 16B per lane; lds is wave-uniform base,
// HW writes at base + lane*16.
__device__ __forceinline__ void load16_lds(const u16* g, u16* lds) {
  __builtin_amdgcn_global_load_lds(
      (const __attribute__((address_space(1))) unsigned int*)g,
      (__attribute__((address_space(3))) unsigned int*)lds, 16, 0, 0);
}

// ---------------- router (+ x -> bf16 conversion) ----------------
__global__ __launch_bounds__(64) void router_kernel(
    const float* __restrict__ x, const float* __restrict__ rw,
    const float* __restrict__ rb, int* __restrict__ counts,
    int* __restrict__ list_token, float* __restrict__ sscore,
    u16* __restrict__ xb) {
  int t = blockIdx.x;
  int lane = threadIdx.x;
  const float* xr = x + (size_t)t * DM;
  u16* xbr = xb + (size_t)t * DM;
  float a[8] = {0.f, 0.f, 0.f, 0.f, 0.f, 0.f, 0.f, 0.f};
  for (int j = lane; j < DM; j += 64) {
    float xv = xr[j];
    xbr[j] = f2bf(xv);
    const float4* r4 = (const float4*)(rw + (size_t)j * 8);
    float4 w0 = r4[0], w1 = r4[1];
    a[0] += xv * w0.x; a[1] += xv * w0.y; a[2] += xv * w0.z; a[3] += xv * w0.w;
    a[4] += xv * w1.x; a[5] += xv * w1.y; a[6] += xv * w1.z; a[7] += xv * w1.w;
  }
#pragma unroll
  for (int e = 0; e < 8; e++)
#pragma unroll
    for (int off = 32; off > 0; off >>= 1) a[e] += __shfl_down(a[e], off);
  if (lane == 0) {
    float l[8];
    float mx = -1e30f;
#pragma unroll
    for (int e = 0; e < 8; e++) { l[e] = a[e] + rb[e]; mx = fmaxf(mx, l[e]); }
    float sum = 0.f;
#pragma unroll
    for (int e = 0; e < 8; e++) { l[e] = __expf(l[e] - mx); sum += l[e]; }
    float inv = 1.f / sum;
    int i1 = 0; float p1 = -1.f;
#pragma unroll
    for (int e = 0; e < 8; e++) if (l[e] > p1) { p1 = l[e]; i1 = e; }
    int i2 = -1; float p2 = -1.f;
#pragma unroll
    for (int e = 0; e < 8; e++) if (e != i1 && l[e] > p2) { p2 = l[e]; i2 = e; }
    int pos1 = atomicAdd(&counts[i1], 1);
    int pos2 = atomicAdd(&counts[i2], 1);
    list_token[i1 * T_TOKENS + pos1] = t;
    list_token[i2 * T_TOKENS + pos2] = t;
    sscore[i1 * T_TOKENS + pos1] = p1 * inv;
    sscore[i2 * T_TOKENS + pos2] = p2 * inv;
  }
}

// ---------------- prefix + selected mask ----------------
__global__ __launch_bounds__(64) void finalize_kernel(const int* __restrict__ counts,
                                                      int* __restrict__ offsets,
                                                      float* __restrict__ sel_out) {
  int tid = threadIdx.x;
  if (tid == 0) {
    int o = 0;
    for (int e = 0; e < NE; e++) { offsets[e] = o; o += counts[e]; }
    offsets[NE] = o;
  }
  if (tid < NE) sel_out[tid] = counts[tid] > 0 ? 1.f : 0.f;
}

// ---------------- transpose + convert weights ----------------
// src fp32 [E][R][C] -> dst bf16 [E][C][R]; 64x32 tiles, u32 stores.
__global__ __launch_bounds__(256) void transpose_cvt_kernel(
    const float* __restrict__ src, u16* __restrict__ dst, int R, int C) {
  __shared__ float tile[64][33];
  int e = blockIdx.z;
  const float* s = src + (size_t)e * R * C;
  u16* d = dst + (size_t)e * R * C;
  int c0 = blockIdx.x * 32, r0 = blockIdx.y * 64;
  int tx = threadIdx.x, ty = threadIdx.y;  // (32, 8)
#pragma unroll
  for (int i = 0; i < 8; i++) {
    int r = r0 + ty + i * 8;
    tile[ty + i * 8][tx] = s[(size_t)r * C + c0 + tx];
  }
  __syncthreads();
#pragma unroll
  for (int i = 0; i < 4; i++) {
    int c = c0 + ty + i * 8;
    unsigned lo = f2bf(tile[2 * tx][ty + i * 8]);
    unsigned hi = f2bf(tile[2 * tx + 1][ty + i * 8]);
    *(unsigned*)&d[(size_t)c * R + r0 + 2 * tx] = lo | (hi << 16);
  }
}

// ---------------- GEMM1: gathered x @ w1t -> gelu -> H (bf16) ----------------
// grid: (DF/128, 64, NE), block 256
__global__ __launch_bounds__(256) void gemm1_kernel(
    const u16* __restrict__ xb, const u16* __restrict__ w1t,
    const float* __restrict__ b1, const int* __restrict__ counts,
    const int* __restrict__ offsets, const int* __restrict__ list_token,
    u16* __restrict__ H) {
  int e = blockIdx.z;
  int cnt = counts[e];
  int r0 = blockIdx.y * 128;
  if (r0 >= cnt) return;
  int n0 = blockIdx.x * 128;
  int rem = cnt - r0;

  __shared__ __align__(16) u16 As[128 * 32];
  __shared__ __align__(16) u16 Bs[128 * 32];

  int tid = threadIdx.x;
  int ra0 = tid >> 2, ca0 = tid & 3;
  int ra1 = ra0 + 64;
  const int* lst = list_token + e * T_TOKENS + r0;
  int tok0 = (ra0 < rem) ? lst[ra0] : lst[0];
  int tok1 = (ra1 < rem) ? lst[ra1] : lst[0];
  const u16* gA0 = xb + (size_t)tok0 * DM + ca0 * 8;
  const u16* gA1 = xb + (size_t)tok1 * DM + ca0 * 8;
  const u16* gB0 = w1t + ((size_t)e * DF + n0 + ra0) * DM + ca0 * 8;
  const u16* gB1 = w1t + ((size_t)e * DF + n0 + ra1) * DM + ca0 * 8;

  int lane = tid & 63, wv = tid >> 6;
  u16* ldsA0 = As + wv * 512;
  u16* ldsA1 = As + 2048 + wv * 512;
  u16* ldsB0 = Bs + wv * 512;
  u16* ldsB1 = Bs + 2048 + wv * 512;

  int wm = (wv >> 1) * 64, wn = (wv & 1) * 64;
  int ml = lane & 15, quad = lane >> 4;

  v4f acc[4][4];
#pragma unroll
  for (int i = 0; i < 4; i++)
#pragma unroll
    for (int j = 0; j < 4; j++) acc[i][j] = (v4f){0.f, 0.f, 0.f, 0.f};

  for (int k0 = 0; k0 < DM; k0 += 32) {
    load16_lds(gA0 + k0, ldsA0);
    load16_lds(gA1 + k0, ldsA1);
    load16_lds(gB0 + k0, ldsB0);
    load16_lds(gB1 + k0, ldsB1);
    __syncthreads();
    v8s af[4], bf[4];
#pragma unroll
    for (int i = 0; i < 4; i++)
      af[i] = *(const v8s*)&As[(wm + i * 16 + ml) * 32 + quad * 8];
#pragma unroll
    for (int j = 0; j < 4; j++)
      bf[j] = *(const v8s*)&Bs[(wn + j * 16 + ml) * 32 + quad * 8];
#pragma unroll
    for (int i = 0; i < 4; i++)
#pragma unroll
      for (int j = 0; j < 4; j++)
        acc[i][j] = __builtin_amdgcn_mfma_f32_16x16x32_bf16(af[i], bf[j], acc[i][j], 0, 0, 0);
    __syncthreads();
  }

  int slotbase = offsets[e] + r0;
#pragma unroll
  for (int i = 0; i < 4; i++) {
    int rbase = wm + i * 16 + quad * 4;
#pragma unroll
    for (int j = 0; j < 4; j++) {
      int cc = n0 + wn + j * 16 + ml;
      float bias = b1[e * DF + cc];
#pragma unroll
      for (int r = 0; r < 4; r++) {
        int row = rbase + r;
        float v = acc[i][j][r] + bias;
        float u = 0.7978845608028654f * (v + 0.044715f * v * v * v);
        float h = v / (1.f + __expf(-2.f * u));  // v * sigmoid(2u) == tanh-gelu
        float hp = __shfl_xor(h, 1);             // partner column value
        if (((ml & 1) == 0) && row < rem) {
          unsigned pk = (unsigned)f2bf(h) | ((unsigned)f2bf(hp) << 16);
          *(unsigned*)&H[(size_t)(slotbase + row) * DF + cc] = pk;
        }
      }
    }
  }
}

// ---------------- GEMM2: H @ w2t, split-K=2, scaled atomic combine ----------------
// grid: (DM/128, 128, NE), block 256. y encodes (m_tile, k_half).
__global__ __launch_bounds__(256) void gemm2_kernel(
    const u16* __restrict__ H, const u16* __restrict__ w2t,
    const float* __restrict__ b2, const int* __restrict__ counts,
    const int* __restrict__ offsets, const int* __restrict__ list_token,
    const float* __restrict__ sscore, float* __restrict__ acc_out) {
  int e = blockIdx.z;
  int cnt = counts[e];
  int kh = blockIdx.y & 1;
  int r0 = (blockIdx.y >> 1) * 128;
  if (r0 >= cnt) return;
  int n0 = blockIdx.x * 128;
  int rem = cnt - r0;
  int slotbase = offsets[e] + r0;

  __shared__ __align__(16) u16 As[128 * 32];
  __shared__ __align__(16) u16 Bs[128 * 32];

  int tid = threadIdx.x;
  int ra0 = tid >> 2, ca0 = tid & 3;
  int ra1 = ra0 + 64;
  int ar0 = (ra0 < rem) ? ra0 : 0;
  int ar1 = (ra1 < rem) ? ra1 : 0;
  const u16* gA0 = H + (size_t)(slotbase + ar0) * DF + ca0 * 8;
  const u16* gA1 = H + (size_t)(slotbase + ar1) * DF + ca0 * 8;
  const u16* gB0 = w2t + ((size_t)e * DM + n0 + ra0) * DF + ca0 * 8;
  const u16* gB1 = w2t + ((size_t)e * DM + n0 + ra1) * DF + ca0 * 8;

  int lane = tid & 63, wv = tid >> 6;
  u16* ldsA0 = As + wv * 512;
  u16* ldsA1 = As + 2048 + wv * 512;
  u16* ldsB0 = Bs + wv * 512;
  u16* ldsB1 = Bs + 2048 + wv * 512;

  int wm = (wv >> 1) * 64, wn = (wv & 1) * 64;
  int ml = lane & 15, quad = lane >> 4;

  v4f acc[4][4];
#pragma unroll
  for (int i = 0; i < 4; i++)
#pragma unroll
    for (int j = 0; j < 4; j++) acc[i][j] = (v4f){0.f, 0.f, 0.f, 0.f};

  int kbase = kh * (DF / 2);
  for (int k0 = kbase; k0 < kbase + DF / 2; k0 += 32) {
    load16_lds(gA0 + k0, ldsA0);
    load16_lds(gA1 + k0, ldsA1);
    load16_lds(gB0 + k0, ldsB0);
    load16_lds(gB1 + k0, ldsB1);
    __syncthreads();
    v8s af[4], bf[4];
#pragma unroll
    for (int i = 0; i < 4; i++)
      af[i] = *(const v8s*)&As[(wm + i * 16 + ml) * 32 + quad * 8];
#pragma unroll
    for (int j = 0; j < 4; j++)
      bf[j] = *(const v8s*)&Bs[(wn + j * 16 + ml) * 32 + quad * 8];
#pragma unroll
    for (int i = 0; i < 4; i++)
#pragma unroll
      for (int j = 0; j < 4; j++)
        acc[i][j] = __builtin_amdgcn_mfma_f32_16x16x32_bf16(af[i], bf[j], acc[i][j], 0, 0, 0);
    __syncthreads();
  }

  // epilogue: scaled atomic accumulate into acc_out[token][cc]
  const int* lst = list_token + e * T_TOKENS + r0;
  const float* ssc = sscore + e * T_TOKENS + r0;
#pragma unroll
  for (int i = 0; i < 4; i++) {
    int rbase = wm + i * 16 + quad * 4;
#pragma unroll
    for (int r = 0; r < 4; r++) {
      int row = rbase + r;
      if (row < rem) {
        int tok = lst[row];
        float sc = ssc[row];
        float* dst = acc_out + (size_t)tok * DM;
#pragma unroll
        for (int j = 0; j < 4; j++) {
          int cc = n0 + wn + j * 16 + ml;
          float v = acc[i][j][r];
          if (kh == 0) v += b2[e * DM + cc];
          atomicAdd(dst + cc, sc * v);
        }
      }
    }
  }
}

// ---------------- residual + combine + LayerNorm ----------------
__global__ __launch_bounds__(256) void ln_kernel(
    const float* __restrict__ x, const float* __restrict__ acc_in,
    const float* __restrict__ gamma, const float* __restrict__ beta,
    float* __restrict__ out) {
  int t = blockIdx.x;
  int tid = threadIdx.x;
  float4 xv = ((const float4*)(x + (size_t)t * DM))[tid];
  float4 av = ((const float4*)(acc_in + (size_t)t * DM))[tid];
  float4 y;
  y.x = xv.x + av.x;
  y.y = xv.y + av.y;
  y.z = xv.z + av.z;
  y.w = xv.w + av.w;
  float s = y.x + y.y + y.z + y.w;
  float ss = y.x * y.x + y.y * y.y + y.z * y.z + y.w * y.w;
#pragma unroll
  for (int off = 32; off > 0; off >>= 1) {
    s += __shfl_down(s, off);
    ss += __shfl_down(ss, off);
  }
  __shared__ float red[10];
  int wid = tid >> 6, lane = tid & 63;
  if (lane == 0) { red[wid] = s; red[4 + wid] = ss; }
  __syncthreads();
  if (tid == 0) {
    float S = red[0] + red[1] + red[2] + red[3];
    float SS = red[4] + red[5] + red[6] + red[7];
    float mu = S * (1.f / DM);
    float var = SS * (1.f / DM) - mu * mu;
    red[8] = mu;
    red[9] = rsqrtf(var + 1e-5f);
  }
  __syncthreads();
  float mu = red[8], rs = red[9];
  float4 g = ((const float4*)gamma)[tid];
  float4 b = ((const float4*)beta)[tid];
  float4 z;
  z.x = (y.x - mu) * rs * g.x + b.x;
  z.y = (y.y - mu) * rs * g.y + b.y;
  z.z = (y.z - mu) * rs * g.z + b.z;
  z.w = (y.w - mu) * rs * g.w + b.w;
  ((float4*)(out + (size_t)t * DM))[tid] = z;
}

// ---------------- launch ----------------
extern "C" void kernel_launch(void* const* d_in, const int* in_sizes, int n_in,
                              void* d_out, int out_size, void* d_ws, size_t ws_size,
                              hipStream_t stream) {
  const float* x = (const float*)d_in[0];
  const float* rw = (const float*)d_in[1];
  const float* rb = (const float*)d_in[2];
  const float* w1 = (const float*)d_in[3];
  const float* b1 = (const float*)d_in[4];
  const float* w2 = (const float*)d_in[5];
  const float* b2 = (const float*)d_in[6];
  const float* gamma = (const float*)d_in[7];
  const float* beta = (const float*)d_in[8];
  float* out = (float*)d_out;

  char* ws = (char*)d_ws;
  // layout (bytes):
  //   counts      @ 0         (32)
  //   offsets     @ 256       (36)
  //   list_token  @ 4096      (262144)
  //   sscore      @ 266240    (262144)
  //   xb   bf16   @ 1048576   (16777216)
  //   w1t  bf16   @ 17825792  (67108864)
  //   w2t  bf16   @ 84934656  (67108864)
  //   H    bf16   @ 152043520 (134217728)
  //   acc  f32    @ 286261248 (33554432)  -> total 319815680
  int* counts = (int*)(ws + 0);
  int* offsets = (int*)(ws + 256);
  int* list_token = (int*)(ws + 4096);
  float* sscore = (float*)(ws + 266240);
  u16* xb = (u16*)(ws + 1048576);
  u16* w1t = (u16*)(ws + 17825792);
  u16* w2t = (u16*)(ws + 84934656);
  u16* H = (u16*)(ws + 152043520);
  float* acc = (float*)(ws + 286261248);

  hipMemsetAsync(counts, 0, NE * sizeof(int), stream);
  hipMemsetAsync(acc, 0, (size_t)T_TOKENS * DM * sizeof(float), stream);

  router_kernel<<<dim3(T_TOKENS), dim3(64), 0, stream>>>(x, rw, rb, counts,
                                                         list_token, sscore, xb);
  finalize_kernel<<<dim3(1), dim3(64), 0, stream>>>(
      counts, offsets, out + (size_t)T_TOKENS * DM);
  // w1 [E][1024][4096] -> w1t [E][4096][1024]
  transpose_cvt_kernel<<<dim3(128, 16, NE), dim3(32, 8), 0, stream>>>(w1, w1t, DM, DF);
  // w2 [E][4096][1024] -> w2t [E][1024][4096]
  transpose_cvt_kernel<<<dim3(32, 64, NE), dim3(32, 8), 0, stream>>>(w2, w2t, DF, DM);

  gemm1_kernel<<<dim3(DF / 128, 64, NE), dim3(256), 0, stream>>>(
      xb, w1t, b1, counts, offsets, list_token, H);
  gemm2_kernel<<<dim3(DM / 128, 128, NE), dim3(256), 0, stream>>>(
      H, w2t, b2, counts, offsets, list_token, sscore, acc);
  ln_kernel<<<dim3(T_TOKENS), dim3(256), 0, stream>>>(x, acc, gamma, beta, out);
}

// Round 4
// 1009.967 us; speedup vs baseline: 1.1761x; 1.1761x over previous
//
#include <hip/hip_runtime.h>

// MoE block: router(top-2 of 8) -> per-expert [M,1024]@[1024,4096] GELU
// -> [M,4096]@[4096,1024] -> scale/combine -> residual + LayerNorm.
// bf16 MFMA (16x16x32), fp32 router/accum/epilogue.
// R4: gemm2/LN reverted to R2 (plain partial stores + LN gather; the R3
//     scatter-atomic combine regressed 260->435us). Fast 64x64 transpose
//     (float4 loads, stride-65 LDS, uint4 stores). Router 4 tokens/block.

#define T_TOKENS 8192
#define DM 1024
#define DF 4096
#define NE 8

typedef unsigned short u16;
typedef short v8s __attribute__((ext_vector_type(8)));
typedef float v4f __attribute__((ext_vector_type(4)));

__device__ __forceinline__ u16 f2bf(float f) {
  unsigned u = __float_as_uint(f);
  u += 0x7FFFu + ((u >> 16) & 1u);
  return (u16)(u >> 16);
}

// async global -> LDS, 16B per lane; lds is wave-uniform base,
// HW writes at base + lane*16.
__device__ __forceinline__ void load16_lds(const u16* g, u16* lds) {
  __builtin_amdgcn_global_load_lds(
      (const __attribute__((address_space(1))) unsigned int*)g,
      (__attribute__((address_space(3))) unsigned int*)lds, 16, 0, 0);
}

// ---------------- router (+ x -> bf16 conversion), 4 tokens/block ----------------
__global__ __launch_bounds__(256) void router_kernel(
    const float* __restrict__ x, const float* __restrict__ rw,
    const float* __restrict__ rb, int* __restrict__ counts,
    int* __restrict__ list_token, int* __restrict__ epos,
    float* __restrict__ escore, u16* __restrict__ xb) {
  int w = threadIdx.x >> 6, lane = threadIdx.x & 63;
  int t = blockIdx.x * 4 + w;
  const float* xr = x + (size_t)t * DM;
  u16* xbr = xb + (size_t)t * DM;
  float a[8] = {0.f, 0.f, 0.f, 0.f, 0.f, 0.f, 0.f, 0.f};
  for (int j = lane; j < DM; j += 64) {
    float xv = xr[j];
    xbr[j] = f2bf(xv);
    const float4* r4 = (const float4*)(rw + (size_t)j * 8);
    float4 w0 = r4[0], w1 = r4[1];
    a[0] += xv * w0.x; a[1] += xv * w0.y; a[2] += xv * w0.z; a[3] += xv * w0.w;
    a[4] += xv * w1.x; a[5] += xv * w1.y; a[6] += xv * w1.z; a[7] += xv * w1.w;
  }
#pragma unroll
  for (int e = 0; e < 8; e++)
#pragma unroll
    for (int off = 32; off > 0; off >>= 1) a[e] += __shfl_down(a[e], off);
  if (lane == 0) {
    float l[8];
    float mx = -1e30f;
#pragma unroll
    for (int e = 0; e < 8; e++) { l[e] = a[e] + rb[e]; mx = fmaxf(mx, l[e]); }
    float sum = 0.f;
#pragma unroll
    for (int e = 0; e < 8; e++) { l[e] = __expf(l[e] - mx); sum += l[e]; }
    float inv = 1.f / sum;
    int i1 = 0; float p1 = -1.f;
#pragma unroll
    for (int e = 0; e < 8; e++) if (l[e] > p1) { p1 = l[e]; i1 = e; }
    int i2 = -1; float p2 = -1.f;
#pragma unroll
    for (int e = 0; e < 8; e++) if (e != i1 && l[e] > p2) { p2 = l[e]; i2 = e; }
    int pos1 = atomicAdd(&counts[i1], 1);
    int pos2 = atomicAdd(&counts[i2], 1);
    list_token[i1 * T_TOKENS + pos1] = t;
    list_token[i2 * T_TOKENS + pos2] = t;
    epos[2 * t] = (i1 << 16) | pos1;
    epos[2 * t + 1] = (i2 << 16) | pos2;
    escore[2 * t] = p1 * inv;
    escore[2 * t + 1] = p2 * inv;
  }
}

// ---------------- prefix + selected mask ----------------
__global__ __launch_bounds__(64) void finalize_kernel(const int* __restrict__ counts,
                                                      int* __restrict__ offsets,
                                                      float* __restrict__ sel_out) {
  int tid = threadIdx.x;
  if (tid == 0) {
    int o = 0;
    for (int e = 0; e < NE; e++) { offsets[e] = o; o += counts[e]; }
    offsets[NE] = o;
  }
  if (tid < NE) sel_out[tid] = counts[tid] > 0 ? 1.f : 0.f;
}

// ---------------- transpose + convert weights ----------------
// src fp32 [E][R][C] -> dst bf16 [E][C][R]; 64x64 tiles.
// Phase1: float4 coalesced loads, stride-65 LDS (<=2-way banks, free).
// Phase2: 8x b32 column reads (<=2-way), pack 8 bf16, uint4 store
//         (8 lanes x 16B = 128B contiguous segments).
__global__ __launch_bounds__(256) void transpose_cvt_kernel(
    const float* __restrict__ src, u16* __restrict__ dst, int R, int C) {
  __shared__ float tile[64 * 65];
  int e = blockIdx.z;
  const float* s = src + (size_t)e * R * C;
  u16* d = dst + (size_t)e * R * C;
  int r0 = blockIdx.y * 64, c0 = blockIdx.x * 64;
  int tid = threadIdx.x;
  int pr = tid >> 4, pc4 = (tid & 15) * 4;
#pragma unroll
  for (int i = 0; i < 4; i++) {
    int r = pr + i * 16;
    float4 v = *(const float4*)(s + (size_t)(r0 + r) * C + c0 + pc4);
    tile[r * 65 + pc4] = v.x;
    tile[r * 65 + pc4 + 1] = v.y;
    tile[r * 65 + pc4 + 2] = v.z;
    tile[r * 65 + pc4 + 3] = v.w;
  }
  __syncthreads();
  int r8 = (tid & 7) * 8, cb = tid >> 3;  // cb 0..31
#pragma unroll
  for (int i = 0; i < 2; i++) {
    int c = cb + i * 32;
    unsigned pk0 = (unsigned)f2bf(tile[(r8 + 0) * 65 + c]) |
                   ((unsigned)f2bf(tile[(r8 + 1) * 65 + c]) << 16);
    unsigned pk1 = (unsigned)f2bf(tile[(r8 + 2) * 65 + c]) |
                   ((unsigned)f2bf(tile[(r8 + 3) * 65 + c]) << 16);
    unsigned pk2 = (unsigned)f2bf(tile[(r8 + 4) * 65 + c]) |
                   ((unsigned)f2bf(tile[(r8 + 5) * 65 + c]) << 16);
    unsigned pk3 = (unsigned)f2bf(tile[(r8 + 6) * 65 + c]) |
                   ((unsigned)f2bf(tile[(r8 + 7) * 65 + c]) << 16);
    *(uint4*)(d + (size_t)(c0 + c) * R + r0 + r8) = make_uint4(pk0, pk1, pk2, pk3);
  }
}

// ---------------- GEMM1: gathered x @ w1t -> gelu -> H (bf16) ----------------
// grid: (DF/128, 64, NE), block 256
__global__ __launch_bounds__(256) void gemm1_kernel(
    const u16* __restrict__ xb, const u16* __restrict__ w1t,
    const float* __restrict__ b1, const int* __restrict__ counts,
    const int* __restrict__ offsets, const int* __restrict__ list_token,
    u16* __restrict__ H) {
  int e = blockIdx.z;
  int cnt = counts[e];
  int r0 = blockIdx.y * 128;
  if (r0 >= cnt) return;
  int n0 = blockIdx.x * 128;
  int rem = cnt - r0;

  __shared__ __align__(16) u16 As[128 * 32];
  __shared__ __align__(16) u16 Bs[128 * 32];

  int tid = threadIdx.x;
  int ra0 = tid >> 2, ca0 = tid & 3;
  int ra1 = ra0 + 64;
  const int* lst = list_token + e * T_TOKENS + r0;
  int tok0 = (ra0 < rem) ? lst[ra0] : lst[0];
  int tok1 = (ra1 < rem) ? lst[ra1] : lst[0];
  const u16* gA0 = xb + (size_t)tok0 * DM + ca0 * 8;
  const u16* gA1 = xb + (size_t)tok1 * DM + ca0 * 8;
  const u16* gB0 = w1t + ((size_t)e * DF + n0 + ra0) * DM + ca0 * 8;
  const u16* gB1 = w1t + ((size_t)e * DF + n0 + ra1) * DM + ca0 * 8;

  int lane = tid & 63, wv = tid >> 6;
  u16* ldsA0 = As + wv * 512;
  u16* ldsA1 = As + 2048 + wv * 512;
  u16* ldsB0 = Bs + wv * 512;
  u16* ldsB1 = Bs + 2048 + wv * 512;

  int wm = (wv >> 1) * 64, wn = (wv & 1) * 64;
  int ml = lane & 15, quad = lane >> 4;

  v4f acc[4][4];
#pragma unroll
  for (int i = 0; i < 4; i++)
#pragma unroll
    for (int j = 0; j < 4; j++) acc[i][j] = (v4f){0.f, 0.f, 0.f, 0.f};

  for (int k0 = 0; k0 < DM; k0 += 32) {
    load16_lds(gA0 + k0, ldsA0);
    load16_lds(gA1 + k0, ldsA1);
    load16_lds(gB0 + k0, ldsB0);
    load16_lds(gB1 + k0, ldsB1);
    __syncthreads();
    v8s af[4], bf[4];
#pragma unroll
    for (int i = 0; i < 4; i++)
      af[i] = *(const v8s*)&As[(wm + i * 16 + ml) * 32 + quad * 8];
#pragma unroll
    for (int j = 0; j < 4; j++)
      bf[j] = *(const v8s*)&Bs[(wn + j * 16 + ml) * 32 + quad * 8];
#pragma unroll
    for (int i = 0; i < 4; i++)
#pragma unroll
      for (int j = 0; j < 4; j++)
        acc[i][j] = __builtin_amdgcn_mfma_f32_16x16x32_bf16(af[i], bf[j], acc[i][j], 0, 0, 0);
    __syncthreads();
  }

  int slotbase = offsets[e] + r0;
#pragma unroll
  for (int i = 0; i < 4; i++) {
    int rbase = wm + i * 16 + quad * 4;
#pragma unroll
    for (int j = 0; j < 4; j++) {
      int cc = n0 + wn + j * 16 + ml;
      float bias = b1[e * DF + cc];
#pragma unroll
      for (int r = 0; r < 4; r++) {
        int row = rbase + r;
        float v = acc[i][j][r] + bias;
        float u = 0.7978845608028654f * (v + 0.044715f * v * v * v);
        float h = v / (1.f + __expf(-2.f * u));  // v * sigmoid(2u) == tanh-gelu
        float hp = __shfl_xor(h, 1);             // partner column value
        if (((ml & 1) == 0) && row < rem) {
          unsigned pk = (unsigned)f2bf(h) | ((unsigned)f2bf(hp) << 16);
          *(unsigned*)&H[(size_t)(slotbase + row) * DF + cc] = pk;
        }
      }
    }
  }
}

// ---------------- GEMM2: H @ w2t + b2 -> partial (fp32, unscaled) ----------------
// grid: (DM/128, 64, NE), block 256
__global__ __launch_bounds__(256) void gemm2_kernel(
    const u16* __restrict__ H, const u16* __restrict__ w2t,
    const float* __restrict__ b2, const int* __restrict__ counts,
    const int* __restrict__ offsets, float* __restrict__ partial) {
  int e = blockIdx.z;
  int cnt = counts[e];
  int r0 = blockIdx.y * 128;
  if (r0 >= cnt) return;
  int n0 = blockIdx.x * 128;
  int rem = cnt - r0;
  int slotbase = offsets[e] + r0;

  __shared__ __align__(16) u16 As[128 * 32];
  __shared__ __align__(16) u16 Bs[128 * 32];

  int tid = threadIdx.x;
  int ra0 = tid >> 2, ca0 = tid & 3;
  int ra1 = ra0 + 64;
  int ar0 = (ra0 < rem) ? ra0 : 0;
  int ar1 = (ra1 < rem) ? ra1 : 0;
  const u16* gA0 = H + (size_t)(slotbase + ar0) * DF + ca0 * 8;
  const u16* gA1 = H + (size_t)(slotbase + ar1) * DF + ca0 * 8;
  const u16* gB0 = w2t + ((size_t)e * DM + n0 + ra0) * DF + ca0 * 8;
  const u16* gB1 = w2t + ((size_t)e * DM + n0 + ra1) * DF + ca0 * 8;

  int lane = tid & 63, wv = tid >> 6;
  u16* ldsA0 = As + wv * 512;
  u16* ldsA1 = As + 2048 + wv * 512;
  u16* ldsB0 = Bs + wv * 512;
  u16* ldsB1 = Bs + 2048 + wv * 512;

  int wm = (wv >> 1) * 64, wn = (wv & 1) * 64;
  int ml = lane & 15, quad = lane >> 4;

  v4f acc[4][4];
#pragma unroll
  for (int i = 0; i < 4; i++)
#pragma unroll
    for (int j = 0; j < 4; j++) acc[i][j] = (v4f){0.f, 0.f, 0.f, 0.f};

  for (int k0 = 0; k0 < DF; k0 += 32) {
    load16_lds(gA0 + k0, ldsA0);
    load16_lds(gA1 + k0, ldsA1);
    load16_lds(gB0 + k0, ldsB0);
    load16_lds(gB1 + k0, ldsB1);
    __syncthreads();
    v8s af[4], bf[4];
#pragma unroll
    for (int i = 0; i < 4; i++)
      af[i] = *(const v8s*)&As[(wm + i * 16 + ml) * 32 + quad * 8];
#pragma unroll
    for (int j = 0; j < 4; j++)
      bf[j] = *(const v8s*)&Bs[(wn + j * 16 + ml) * 32 + quad * 8];
#pragma unroll
    for (int i = 0; i < 4; i++)
#pragma unroll
      for (int j = 0; j < 4; j++)
        acc[i][j] = __builtin_amdgcn_mfma_f32_16x16x32_bf16(af[i], bf[j], acc[i][j], 0, 0, 0);
    __syncthreads();
  }

#pragma unroll
  for (int i = 0; i < 4; i++) {
    int rbase = wm + i * 16 + quad * 4;
#pragma unroll
    for (int j = 0; j < 4; j++) {
      int cc = n0 + wn + j * 16 + ml;
      float bias = b2[e * DM + cc];
#pragma unroll
      for (int r = 0; r < 4; r++) {
        int row = rbase + r;
        if (row < rem)
          partial[(size_t)(slotbase + row) * DM + cc] = acc[i][j][r] + bias;
      }
    }
  }
}

// ---------------- residual + combine + LayerNorm ----------------
__global__ __launch_bounds__(256) void ln_kernel(
    const float* __restrict__ x, const float* __restrict__ partial,
    const int* __restrict__ offsets, const int* __restrict__ epos,
    const float* __restrict__ escore, const float* __restrict__ gamma,
    const float* __restrict__ beta, float* __restrict__ out) {
  int t = blockIdx.x;
  int tid = threadIdx.x;
  int e0p = epos[2 * t], e1p = epos[2 * t + 1];
  float s0 = escore[2 * t], s1 = escore[2 * t + 1];
  size_t row0 = (size_t)offsets[e0p >> 16] + (e0p & 0xFFFF);
  size_t row1 = (size_t)offsets[e1p >> 16] + (e1p & 0xFFFF);
  float4 xv = ((const float4*)(x + (size_t)t * DM))[tid];
  float4 p0 = ((const float4*)(partial + row0 * DM))[tid];
  float4 p1 = ((const float4*)(partial + row1 * DM))[tid];
  float4 y;
  y.x = xv.x + s0 * p0.x + s1 * p1.x;
  y.y = xv.y + s0 * p0.y + s1 * p1.y;
  y.z = xv.z + s0 * p0.z + s1 * p1.z;
  y.w = xv.w + s0 * p0.w + s1 * p1.w;
  float s = y.x + y.y + y.z + y.w;
  float ss = y.x * y.x + y.y * y.y + y.z * y.z + y.w * y.w;
#pragma unroll
  for (int off = 32; off > 0; off >>= 1) {
    s += __shfl_down(s, off);
    ss += __shfl_down(ss, off);
  }
  __shared__ float red[10];
  int wid = tid >> 6, lane = tid & 63;
  if (lane == 0) { red[wid] = s; red[4 + wid] = ss; }
  __syncthreads();
  if (tid == 0) {
    float S = red[0] + red[1] + red[2] + red[3];
    float SS = red[4] + red[5] + red[6] + red[7];
    float mu = S * (1.f / DM);
    float var = SS * (1.f / DM) - mu * mu;
    red[8] = mu;
    red[9] = rsqrtf(var + 1e-5f);
  }
  __syncthreads();
  float mu = red[8], rs = red[9];
  float4 g = ((const float4*)gamma)[tid];
  float4 b = ((const float4*)beta)[tid];
  float4 z;
  z.x = (y.x - mu) * rs * g.x + b.x;
  z.y = (y.y - mu) * rs * g.y + b.y;
  z.z = (y.z - mu) * rs * g.z + b.z;
  z.w = (y.w - mu) * rs * g.w + b.w;
  ((float4*)(out + (size_t)t * DM))[tid] = z;
}

// ---------------- launch ----------------
extern "C" void kernel_launch(void* const* d_in, const int* in_sizes, int n_in,
                              void* d_out, int out_size, void* d_ws, size_t ws_size,
                              hipStream_t stream) {
  const float* x = (const float*)d_in[0];
  const float* rw = (const float*)d_in[1];
  const float* rb = (const float*)d_in[2];
  const float* w1 = (const float*)d_in[3];
  const float* b1 = (const float*)d_in[4];
  const float* w2 = (const float*)d_in[5];
  const float* b2 = (const float*)d_in[6];
  const float* gamma = (const float*)d_in[7];
  const float* beta = (const float*)d_in[8];
  float* out = (float*)d_out;

  char* ws = (char*)d_ws;
  // layout (bytes):
  //   counts      @ 0         (32)
  //   offsets     @ 256       (36)
  //   list_token  @ 4096      (262144)
  //   epos        @ 266240    (65536)
  //   escore      @ 331776    (65536)
  //   xb   bf16   @ 1048576   (16777216)
  //   w1t  bf16   @ 17825792  (67108864)
  //   w2t  bf16   @ 84934656  (67108864)
  //   H    bf16   @ 152043520 (134217728)
  //   partial f32 @ 286261248 (67108864)  -> total 353370112
  int* counts = (int*)(ws + 0);
  int* offsets = (int*)(ws + 256);
  int* list_token = (int*)(ws + 4096);
  int* epos = (int*)(ws + 266240);
  float* escore = (float*)(ws + 331776);
  u16* xb = (u16*)(ws + 1048576);
  u16* w1t = (u16*)(ws + 17825792);
  u16* w2t = (u16*)(ws + 84934656);
  u16* H = (u16*)(ws + 152043520);
  float* partial = (float*)(ws + 286261248);

  hipMemsetAsync(counts, 0, NE * sizeof(int), stream);

  router_kernel<<<dim3(T_TOKENS / 4), dim3(256), 0, stream>>>(
      x, rw, rb, counts, list_token, epos, escore, xb);
  finalize_kernel<<<dim3(1), dim3(64), 0, stream>>>(
      counts, offsets, out + (size_t)T_TOKENS * DM);
  // w1 [E][1024][4096] -> w1t [E][4096][1024]
  transpose_cvt_kernel<<<dim3(64, 16, NE), dim3(256), 0, stream>>>(w1, w1t, DM, DF);
  // w2 [E][4096][1024] -> w2t [E][1024][4096]
  transpose_cvt_kernel<<<dim3(16, 64, NE), dim3(256), 0, stream>>>(w2, w2t, DF, DM);

  gemm1_kernel<<<dim3(DF / 128, 64, NE), dim3(256), 0, stream>>>(
      xb, w1t, b1, counts, offsets, list_token, H);
  gemm2_kernel<<<dim3(DM / 128, 64, NE), dim3(256), 0, stream>>>(
      H, w2t, b2, counts, offsets, partial);
  ln_kernel<<<dim3(T_TOKENS), dim3(256), 0, stream>>>(x, partial, offsets, epos,
                                                      escore, gamma, beta, out);
}